// Round 12
// baseline (229.841 us; speedup 1.0000x reference)
//
#include <hip/hip_runtime.h>
#include <math.h>

#define B_ 8
#define S_ 2048
#define D_ 512
#define HSZ (B_ * S_ * D_)   // 8,388,608 elements

typedef _Float16 half8 __attribute__((ext_vector_type(8)));
typedef _Float16 half4h __attribute__((ext_vector_type(4)));
typedef __fp16 fp16x2 __attribute__((ext_vector_type(2)));
typedef float f32x4 __attribute__((ext_vector_type(4)));
typedef float f32x16 __attribute__((ext_vector_type(16)));
typedef unsigned int u32;
typedef u32 u32x4 __attribute__((ext_vector_type(4)));

constexpr float INV_SCALE = 0.044194173824159216f; // 1/sqrt(512)

__device__ __forceinline__ u32 pk16(float a, float b) {
    fp16x2 r = __builtin_amdgcn_cvt_pkrtz(a, b);
    union { fp16x2 h; u32 u; } U; U.h = r; return U.u;
}

// ================= cvtW: W -> WT (frag-tiled W^T), 64 blocks (r10-verified) =
__global__ __launch_bounds__(256) void cvtW(const float* __restrict__ W,
                                            _Float16* __restrict__ WT) {
    __shared__ float T[64 * 65];
    const int tid = threadIdx.x;
    const int r = blockIdx.x;
    const int t0 = (r >> 3) * 64, d0 = (r & 7) * 64;   // t0 = k-range, d0 = n-range

#pragma unroll
    for (int it = 0; it < 4; ++it) {
        int flat = it * 256 + tid;
        int row = flat >> 4, c4 = (flat & 15) * 4;
        float4 v = *(const float4*)(W + (size_t)(t0 + row) * 512 + d0 + c4);
        T[row * 65 + c4 + 0] = v.x; T[row * 65 + c4 + 1] = v.y;
        T[row * 65 + c4 + 2] = v.z; T[row * 65 + c4 + 3] = v.w;
    }
    __syncthreads();
#pragma unroll
    for (int it = 0; it < 2; ++it) {
        int flat = it * 256 + tid;
        int d = flat >> 3, c = (flat & 7) * 8;   // n = d0+d, k = t0+c..+7
        half8 hv;
#pragma unroll
        for (int j = 0; j < 8; ++j) hv[j] = (_Float16)T[(c + j) * 65 + d];
        int n = d0 + d, k = t0 + c;
        int off = ((n >> 5) << 14) | ((k >> 4) << 9) | ((n & 31) << 4) |
                  (((k >> 3) & 1) << 3) | (k & 7);
        *(half8*)(WT + off) = hv;
    }
}

// ================= cvtX: x -> xK + xV frags, contiguous 1KB stores ==========
// gemmF(r10-verified) minus the GEMM: stage x[32][512] f32 -> LDS once; emit
// xV frags (column reads + RNE casts) and xK frags (row reads + RNE casts),
// every global store a contiguous 1KB wave-store. 512 blocks, b=blk&7 (XCD
// mapping matches flashF's consumer side).
__global__ __launch_bounds__(256, 2)
void cvtX(const float* __restrict__ x, _Float16* __restrict__ xK,
          _Float16* __restrict__ xV) {
    __shared__ float T[32 * 516];   // 66,048 B
    const int tid = threadIdx.x;
    const int w = tid >> 6, lane = tid & 63;
    const int r31 = lane & 31, hi = lane >> 5;
    const int laneoff = (r31 << 4) + (hi << 3);
    const int blk = blockIdx.x;
    const int b = blk & 7;
    const int mt = blk >> 3;
    const size_t bb = (size_t)b * (S_ * D_);

    // ---- stage x rows (coalesced float4) ----
    {
        const float* xs = x + bb + (size_t)(mt * 32) * 512;
#pragma unroll
        for (int it = 0; it < 16; ++it) {
            int f = it * 256 + tid;
            int row = f >> 7, c4 = (f & 127) << 2;
            float4 v = *(const float4*)(xs + (size_t)row * 512 + c4);
            *(float4*)&T[row * 516 + c4] = v;
        }
    }
    __syncthreads();

    // ---- xV frags: column reads, RNE casts, contiguous 1KB stores ----
    {
        _Float16* xvb = xV + bb + ((size_t)mt << 14) + (w << 12);
#pragma unroll
        for (int dc = 0; dc < 4; ++dc)
#pragma unroll
            for (int kh = 0; kh < 2; ++kh) {
                int d = w * 128 + dc * 32 + r31;
                half8 v;
#pragma unroll
                for (int j = 0; j < 8; ++j)
                    v[j] = (_Float16)T[(kh * 16 + hi * 8 + j) * 516 + d];
                *(half8*)(xvb + (dc << 10) + (kh << 9) + laneoff) = v;
            }
    }

    // ---- xK frags: row reads, RNE casts, contiguous 1KB stores ----
    {
        _Float16* xkb = xK + bb + ((size_t)mt << 14);
#pragma unroll
        for (int k8 = 0; k8 < 8; ++k8) {
            int kc = k8 * 4 + w;    // wave w owns kc with (kc&3)==w
            const float* tr = &T[r31 * 516 + kc * 16 + hi * 8];
            half8 a;
#pragma unroll
            for (int j = 0; j < 8; ++j) a[j] = (_Float16)tr[j];
            *(half8*)(xkb + (kc << 9) + laneoff) = a;
        }
    }
}

// ================= flashF: fused Q-GEMM prologue + flashP main loop =========
// (r11-verified, 157.6us) — byte-identical.
__global__ __launch_bounds__(256, 2)
void flashF(const _Float16* __restrict__ xK, const _Float16* __restrict__ xV,
            const _Float16* __restrict__ WT, float* __restrict__ out) {
    __shared__ __align__(16) unsigned char SMEM[34816];
    float* Sx = (float*)SMEM;

    const int tid = threadIdx.x;
    const int w = tid >> 6, lane = tid & 63;
    const int r31 = lane & 31, hi = lane >> 5;
    const int laneoff = (r31 << 4) + (hi << 3);
    const int d0w = w * 128;
    const int bx = blockIdx.x;
    const int b = bx & 7;
    const int q0 = (bx >> 3) * 32;
    const size_t xb = (size_t)b * (S_ * D_);

    const _Float16* kbase = xK + xb + (w << 12) + laneoff;
    const _Float16* vbase = xV + xb + (w << 12) + laneoff;

    // ---- prologue A: Q-GEMM for this wave's k-quarter (n in [w*128,+128)) --
    half8 Qr[8];
    {
        const _Float16* aq = xK + xb + ((size_t)(q0 >> 5) << 14) + laneoff;
        const _Float16* wtb = WT + ((w * 4) << 14) + laneoff;
        f32x16 acc[4];
#pragma unroll
        for (int nt = 0; nt < 4; ++nt)
#pragma unroll
            for (int r = 0; r < 16; ++r) acc[nt][r] = 0.f;
#pragma unroll
        for (int kg = 0; kg < 4; ++kg) {
            half8 Ax[8];
#pragma unroll
            for (int k8 = 0; k8 < 8; ++k8)
                Ax[k8] = *(const half8*)(aq + ((kg * 8 + k8) << 9));
#pragma unroll
            for (int k8 = 0; k8 < 8; ++k8) {
                int kc = kg * 8 + k8;
                half8 B0 = *(const half8*)(wtb + (0 << 14) + (kc << 9));
                half8 B1 = *(const half8*)(wtb + (1 << 14) + (kc << 9));
                half8 B2 = *(const half8*)(wtb + (2 << 14) + (kc << 9));
                half8 B3 = *(const half8*)(wtb + (3 << 14) + (kc << 9));
                acc[0] = __builtin_amdgcn_mfma_f32_32x32x16_f16(Ax[k8], B0, acc[0], 0, 0, 0);
                acc[1] = __builtin_amdgcn_mfma_f32_32x32x16_f16(Ax[k8], B1, acc[1], 0, 0, 0);
                acc[2] = __builtin_amdgcn_mfma_f32_32x32x16_f16(Ax[k8], B2, acc[2], 0, 0, 0);
                acc[3] = __builtin_amdgcn_mfma_f32_32x32x16_f16(Ax[k8], B3, acc[3], 0, 0, 0);
            }
        }
        // acc -> Qr via per-nt LDS transpose (same-wave write->read, no barrier)
        float* tw = (float*)SMEM + w * 1152;
#pragma unroll
        for (int nt = 0; nt < 4; ++nt) {
#pragma unroll
            for (int r = 0; r < 16; ++r) {
                int mrow = (r & 3) + ((r >> 2) << 3) + (hi << 2);
                tw[mrow * 36 + r31] = acc[nt][r] * INV_SCALE;
            }
#pragma unroll
            for (int h2 = 0; h2 < 2; ++h2) {
                const float* tr = tw + r31 * 36 + h2 * 16 + hi * 8;
                f32x4 a = *(const f32x4*)(tr);
                f32x4 b4 = *(const f32x4*)(tr + 4);
                half8 q;
#pragma unroll
                for (int j = 0; j < 4; ++j) { q[j] = (_Float16)a[j]; q[4 + j] = (_Float16)b4[j]; }
                Qr[2 * nt + h2] = q;
            }
        }
    }
    __syncthreads();   // transpose patches done before Sx region is reused

    half8 KA[8], KB[8];
    f32x16 sS;

    // ---- prologue B: K(0)->KA, QK(0), Kpre(1)->KB, S-write(0), BAR ----
#pragma unroll
    for (int kc = 0; kc < 8; ++kc)
        KA[kc] = *(const half8*)(kbase + (kc << 9));
    {
        f32x16 s;
#pragma unroll
        for (int r = 0; r < 16; ++r) s[r] = 0.f;
#pragma unroll
        for (int kc = 0; kc < 8; ++kc)
            s = __builtin_amdgcn_mfma_f32_32x32x16_f16(KA[kc], Qr[kc], s, 0, 0, 0);
        sS = s;
    }
#pragma unroll
    for (int kc = 0; kc < 8; ++kc)
        KB[kc] = *(const half8*)(kbase + (1 << 14) + (kc << 9));
    {
        float* sxw = Sx + w * 1024;
#pragma unroll
        for (int r2 = 0; r2 < 4; ++r2) {
            f32x4 v_ = { sS[4 * r2 + 0], sS[4 * r2 + 1], sS[4 * r2 + 2], sS[4 * r2 + 3] };
            *(f32x4*)&sxw[(r2 * 64 + lane) * 4] = v_;
        }
    }
    __syncthreads();

    f32x16 O[4];
#pragma unroll
    for (int dc = 0; dc < 4; ++dc)
#pragma unroll
        for (int r = 0; r < 16; ++r) O[dc][r] = 0.f;
    float m = -1e30f, l = 0.f;

#define SMX_HEAD(TI) \
    half8 Vc[8]; \
    _Pragma("unroll") for (int dc = 0; dc < 4; ++dc) \
    _Pragma("unroll") for (int kh = 0; kh < 2; ++kh) \
        Vc[dc * 2 + kh] = *(const half8*)(vbase + ((TI) << 14) + (dc << 10) + (kh << 9)); \
    float sv[16]; \
    { \
        _Pragma("unroll") for (int i = 0; i < 16; ++i) sv[i] = sS[i]; \
        _Pragma("unroll") for (int pw = 1; pw < 4; ++pw) { \
            const float* sxp = Sx + (((TI) & 1) * 4 + (w ^ pw)) * 1024; \
            _Pragma("unroll") for (int r2 = 0; r2 < 4; ++r2) { \
                f32x4 pp = *(const f32x4*)&sxp[(r2 * 64 + lane) * 4]; \
                _Pragma("unroll") for (int j = 0; j < 4; ++j) sv[4 * r2 + j] += pp[j]; \
            } \
        } \
    } \
    float mt_ = sv[0]; \
    _Pragma("unroll") for (int i = 1; i < 16; ++i) mt_ = fmaxf(mt_, sv[i]); \
    mt_ = fmaxf(mt_, __shfl_xor(mt_, 32)); \
    if (__any(mt_ > m + 8.f)) { \
        float mn = fmaxf(m, mt_); \
        float a_ = __expf(m - mn); \
        l *= a_; \
        _Pragma("unroll") for (int dc = 0; dc < 4; ++dc) \
        _Pragma("unroll") for (int r = 0; r < 16; ++r) O[dc][r] *= a_; \
        m = mn; \
    } \
    float pa[16]; float rs = 0.f; \
    _Pragma("unroll") for (int i = 0; i < 16; ++i) { pa[i] = __expf(sv[i] - m); rs += pa[i]; } \
    l += rs + __shfl_xor(rs, 32);

#define SMX_TAILPART \
    u32 q16[8]; \
    _Pragma("unroll") for (int r2 = 0; r2 < 4; ++r2) { \
        q16[2 * r2 + 0] = pk16(pa[4 * r2 + 0], pa[4 * r2 + 1]); \
        q16[2 * r2 + 1] = pk16(pa[4 * r2 + 2], pa[4 * r2 + 3]); \
    } \
    half8 Pf[2]; \
    _Pragma("unroll") for (int kh = 0; kh < 2; ++kh) { \
        int r2o = 2 * kh + hi, r2s = 2 * kh + (hi ^ 1); \
        u32 rv0 = (u32)__shfl_xor((int)q16[2 * r2s + 0], 32); \
        u32 rv1 = (u32)__shfl_xor((int)q16[2 * r2s + 1], 32); \
        u32 o0 = q16[2 * r2o + 0], o1 = q16[2 * r2o + 1]; \
        union { u32 u[4]; half8 v; } U_; \
        U_.u[0] = hi ? rv0 : o0; U_.u[1] = hi ? rv1 : o1; \
        U_.u[2] = hi ? o0 : rv0; U_.u[3] = hi ? o1 : rv1; \
        Pf[kh] = U_.v; \
    } \
    _Pragma("unroll") for (int dc = 0; dc < 4; ++dc) { \
        O[dc] = __builtin_amdgcn_mfma_f32_32x32x16_f16(Vc[dc * 2 + 0], Pf[0], O[dc], 0, 0, 0); \
        O[dc] = __builtin_amdgcn_mfma_f32_32x32x16_f16(Vc[dc * 2 + 1], Pf[1], O[dc], 0, 0, 0); \
    }

#define PBODY(TI, KRD, KWR) do {                                                \
    SMX_HEAD(TI)                                                                \
    f32x16 sn_;                                                                 \
    {                                                                           \
        f32x16 s_;                                                              \
        _Pragma("unroll") for (int r = 0; r < 16; ++r) s_[r] = 0.f;             \
        _Pragma("unroll") for (int kc = 0; kc < 8; ++kc)                        \
            s_ = __builtin_amdgcn_mfma_f32_32x32x16_f16(KRD[kc], Qr[kc], s_, 0, 0, 0); \
        sn_ = s_;                                                               \
    }                                                                           \
    {                                                                           \
        const int tp2_ = ((TI) + 2) & 63;                                       \
        _Pragma("unroll") for (int kc = 0; kc < 8; ++kc)                        \
            KWR[kc] = *(const half8*)(kbase + (tp2_ << 14) + (kc << 9));        \
    }                                                                           \
    SMX_TAILPART                                                                \
    sS = sn_;                                                                   \
    {                                                                           \
        float* sxw = Sx + ((((TI) + 1) & 1) * 4 + w) * 1024;                    \
        _Pragma("unroll") for (int r2 = 0; r2 < 4; ++r2) {                      \
            f32x4 v_ = { sS[4 * r2 + 0], sS[4 * r2 + 1], sS[4 * r2 + 2], sS[4 * r2 + 3] }; \
            *(f32x4*)&sxw[(r2 * 64 + lane) * 4] = v_;                           \
        }                                                                       \
    }                                                                           \
    __syncthreads();                                                            \
} while (0)

    for (int tp = 0; tp < 31; ++tp) {
        PBODY(2 * tp,     KB, KA);
        PBODY(2 * tp + 1, KA, KB);
    }
    PBODY(62, KB, KA);
    {
        SMX_HEAD(63)
        SMX_TAILPART
    }
#undef PBODY
#undef SMX_HEAD
#undef SMX_TAILPART

    __syncthreads();   // protect Sx region before epilogue overlay

    // ---- epilogue: O^T/l -> 2-phase LDS transpose -> coalesced stores ----
    {
        float inv = 1.0f / l;
        float* ew = (float*)SMEM + w * 2176;   // 32 q-rows x 68 (pad) per wave
        const int qq = lane >> 1, cs = (lane & 1) * 32;
#pragma unroll
        for (int ph = 0; ph < 2; ++ph) {
#pragma unroll
            for (int dc = 0; dc < 2; ++dc)
#pragma unroll
                for (int r = 0; r < 16; ++r) {
                    int dl = dc * 32 + (r & 3) + ((r >> 2) << 3) + (hi << 2);
                    ew[r31 * 68 + dl] = O[ph * 2 + dc][r] * inv;
                }
            float* gp = out + xb + (size_t)(q0 + qq) * 512 + d0w + ph * 64 + cs;
#pragma unroll
            for (int k = 0; k < 8; ++k)
                *(f32x4*)(gp + 4 * k) = *(const f32x4*)&ew[qq * 68 + cs + 4 * k];
        }
    }
}

// ================= fp32 fallback (round 1) ==================================
__global__ __launch_bounds__(256) void xw_gemm_f32(const float* __restrict__ A,
                                                   const float* __restrict__ W,
                                                   float* __restrict__ C) {
    __shared__ float As[16][65];
    __shared__ float Bs[16][64];
    const int tid = threadIdx.x;
    const int row0 = blockIdx.y * 64, col0 = blockIdx.x * 64;
    const int ty = tid / 16, tx = tid % 16;
    float acc[4][4] = {};
    const int ar = tid / 4, ak = (tid % 4) * 4, bk = tid / 16, bn = (tid % 16) * 4;
    for (int k0 = 0; k0 < 512; k0 += 16) {
        float4 a4 = *(const float4*)(A + (size_t)(row0 + ar) * 512 + k0 + ak);
        float4 b4 = *(const float4*)(W + (size_t)(k0 + bk) * 512 + col0 + bn);
        __syncthreads();
        As[ak + 0][ar] = a4.x; As[ak + 1][ar] = a4.y;
        As[ak + 2][ar] = a4.z; As[ak + 3][ar] = a4.w;
        *(float4*)&Bs[bk][bn] = b4;
        __syncthreads();
#pragma unroll
        for (int kk = 0; kk < 16; kk++) {
            float a[4], bv[4];
#pragma unroll
            for (int i = 0; i < 4; i++) a[i] = As[kk][ty * 4 + i];
#pragma unroll
            for (int j = 0; j < 4; j++) bv[j] = Bs[kk][tx * 4 + j];
#pragma unroll
            for (int i = 0; i < 4; i++)
#pragma unroll
                for (int j = 0; j < 4; j++) acc[i][j] += a[i] * bv[j];
        }
    }
#pragma unroll
    for (int i = 0; i < 4; i++) {
        float4 o = make_float4(acc[i][0] * INV_SCALE, acc[i][1] * INV_SCALE,
                               acc[i][2] * INV_SCALE, acc[i][3] * INV_SCALE);
        *(float4*)(C + (size_t)(row0 + ty * 4 + i) * 512 + col0 + tx * 4) = o;
    }
}

__global__ __launch_bounds__(256) void flash_f32(const float* __restrict__ x,
                                                 const float* __restrict__ qw,
                                                 float* __restrict__ out) {
    __shared__ float4 kt[16 * 136];
    const int tid = threadIdx.x;
    const int q = tid >> 3, g = tid & 7;
    const int blk = blockIdx.x;
    const int b = blk >> 6;
    const int qrow = (blk & 63) * 32 + q;
    const size_t xbase = (size_t)b * S_ * D_;
    float qwr[64];
    {
        const float4* p = (const float4*)(qw + xbase + (size_t)qrow * D_ + g * 64);
#pragma unroll
        for (int i4 = 0; i4 < 16; i4++) {
            float4 v = p[i4];
            qwr[4 * i4 + 0] = v.x; qwr[4 * i4 + 1] = v.y;
            qwr[4 * i4 + 2] = v.z; qwr[4 * i4 + 3] = v.w;
        }
    }
    float oa[64];
#pragma unroll
    for (int i = 0; i < 64; i++) oa[i] = 0.f;
    float m = -1e30f, l = 0.f;
    const float4* x4 = (const float4*)(x + xbase);
    for (int t0 = 0; t0 < S_; t0 += 16) {
        __syncthreads();
#pragma unroll
        for (int j = 0; j < 8; j++) {
            int f = tid + j * 256;
            int tt = f >> 7, c = f & 127;
            kt[tt * 136 + (c >> 4) * 17 + (c & 15)] = x4[(size_t)(t0 + tt) * 128 + c];
        }
        __syncthreads();
#pragma unroll 1
        for (int tt = 0; tt < 16; tt++) {
            float4 kv[16];
            const float4* kp = &kt[tt * 136 + g * 17];
#pragma unroll
            for (int i4 = 0; i4 < 16; i4++) kv[i4] = kp[i4];
            float s = 0.f;
#pragma unroll
            for (int i4 = 0; i4 < 16; i4++)
                s += qwr[4 * i4] * kv[i4].x + qwr[4 * i4 + 1] * kv[i4].y
                   + qwr[4 * i4 + 2] * kv[i4].z + qwr[4 * i4 + 3] * kv[i4].w;
            s += __shfl_xor(s, 1, 64); s += __shfl_xor(s, 2, 64); s += __shfl_xor(s, 4, 64);
            if (s > m) {
                float alpha = __expf(m - s);
                l *= alpha;
#pragma unroll
                for (int i = 0; i < 64; i++) oa[i] *= alpha;
                m = s;
            }
            float p = __expf(s - m);
            l += p;
#pragma unroll
            for (int i4 = 0; i4 < 16; i4++) {
                oa[4 * i4 + 0] += p * kv[i4].x; oa[4 * i4 + 1] += p * kv[i4].y;
                oa[4 * i4 + 2] += p * kv[i4].z; oa[4 * i4 + 3] += p * kv[i4].w;
            }
        }
    }
    float inv_l = 1.0f / l;
    float4* op = (float4*)(out + xbase + (size_t)qrow * D_ + g * 64);
#pragma unroll
    for (int i4 = 0; i4 < 16; i4++)
        op[i4] = make_float4(oa[4 * i4] * inv_l, oa[4 * i4 + 1] * inv_l,
                             oa[4 * i4 + 2] * inv_l, oa[4 * i4 + 3] * inv_l);
}

// ================= launch ====================================================
extern "C" void kernel_launch(void* const* d_in, const int* in_sizes, int n_in,
                              void* d_out, int out_size, void* d_ws, size_t ws_size,
                              hipStream_t stream) {
    const float* x = (const float*)d_in[0];
    const float* W = (const float*)d_in[1];
    float* out = (float*)d_out;

    const size_t F16 = (size_t)HSZ * sizeof(_Float16);     // 16,777,216
    const size_t off_xK = 0;
    const size_t off_xV = F16;
    const size_t off_WT = 2 * F16;
    const size_t base   = 2 * F16 + 512 * 512 * sizeof(_Float16);   // 34,078,720

    if (ws_size >= base) {
        _Float16* xK = (_Float16*)((char*)d_ws + off_xK);
        _Float16* xV = (_Float16*)((char*)d_ws + off_xV);
        _Float16* WT = (_Float16*)((char*)d_ws + off_WT);

        cvtW<<<64, 256, 0, stream>>>(W, WT);
        cvtX<<<512, 256, 0, stream>>>(x, xK, xV);
        flashF<<<512, 256, 0, stream>>>(xK, xV, WT, out);
    } else {
        const size_t needf = (size_t)HSZ * sizeof(float);
        float* xw = (ws_size >= needf) ? (float*)d_ws : out;
        dim3 g1(512 / 64, (B_ * S_) / 64);
        xw_gemm_f32<<<g1, 256, 0, stream>>>(x, W, xw);
        flash_f32<<<B_ * (S_ / 32), 256, 0, stream>>>(x, xw, out);
    }
}

// Round 13
// 222.832 us; speedup vs baseline: 1.0315x; 1.0315x over previous
//
#include <hip/hip_runtime.h>
#include <math.h>

#define B_ 8
#define S_ 2048
#define D_ 512
#define HSZ (B_ * S_ * D_)   // 8,388,608 elements

typedef _Float16 half8 __attribute__((ext_vector_type(8)));
typedef _Float16 half4h __attribute__((ext_vector_type(4)));
typedef __fp16 fp16x2 __attribute__((ext_vector_type(2)));
typedef float f32x4 __attribute__((ext_vector_type(4)));
typedef float f32x16 __attribute__((ext_vector_type(16)));
typedef unsigned int u32;
typedef u32 u32x4 __attribute__((ext_vector_type(4)));

constexpr float INV_SCALE = 0.044194173824159216f; // 1/sqrt(512)

__device__ __forceinline__ u32 pk16(float a, float b) {
    fp16x2 r = __builtin_amdgcn_cvt_pkrtz(a, b);
    union { fp16x2 h; u32 u; } U; U.h = r; return U.u;
}

// LDS-only barrier: drains DS ops (cross-wave visibility) but lets global
// register-loads (K-prefetch, V) stay in flight across the barrier. The
// compiler still inserts vmcnt(N) before any USE of those registers.
__device__ __forceinline__ void bar_lds() {
    asm volatile("s_waitcnt lgkmcnt(0)" ::: "memory");
    __builtin_amdgcn_s_barrier();
    asm volatile("" ::: "memory");
}

// ---- frag-tiled layouts (element offsets within one batch) ----
__device__ __forceinline__ int offK(int t, int d) {
    return ((t >> 5) << 14) | (((d >> 7) & 3) << 12) | (((d >> 4) & 7) << 9) |
           ((t & 31) << 4) | (((d >> 3) & 1) << 3) | (d & 7);
}
__device__ __forceinline__ int offV(int t, int d) {
    return ((t >> 5) << 14) | (((d >> 7) & 3) << 12) | (((d >> 5) & 3) << 10) |
           (((t >> 4) & 1) << 9) | ((d & 31) << 4) | (((t >> 3) & 1) << 3) | (t & 7);
}
__device__ __forceinline__ int offWT(int n, int k) {
    return ((n >> 5) << 14) | ((k >> 4) << 9) | ((n & 31) << 4) |
           (((k >> 3) & 1) << 3) | (k & 7);
}

// ================= cvt_all: fp16 convert + frag-tiled emission (r4/r11) =====
__global__ __launch_bounds__(256) void cvt_all(const float* __restrict__ x,
                                               const float* __restrict__ W,
                                               _Float16* __restrict__ xK,
                                               _Float16* __restrict__ xV,
                                               _Float16* __restrict__ WT) {
    __shared__ float T[64 * 65];
    const int tid = threadIdx.x;
    const int blk = blockIdx.x;

    const float* src;
    int t0, d0, isX, bofs = 0;
    if (blk < 2048) {
        int b = blk >> 8;
        int r = blk & 255;
        t0 = (r >> 3) * 64; d0 = (r & 7) * 64;
        src = x + (size_t)b * (S_ * D_);
        bofs = b * (S_ * D_);
        isX = 1;
    } else {
        int r = blk - 2048;
        t0 = (r >> 3) * 64; d0 = (r & 7) * 64;
        src = W;
        isX = 0;
    }

#pragma unroll
    for (int it = 0; it < 4; ++it) {
        int flat = it * 256 + tid;
        int row = flat >> 4, c4 = (flat & 15) * 4;
        float4 v = *(const float4*)(src + (size_t)(t0 + row) * 512 + d0 + c4);
        T[row * 65 + c4 + 0] = v.x; T[row * 65 + c4 + 1] = v.y;
        T[row * 65 + c4 + 2] = v.z; T[row * 65 + c4 + 3] = v.w;
        if (isX) {
            half4h h = { (_Float16)v.x, (_Float16)v.y, (_Float16)v.z, (_Float16)v.w };
            *(half4h*)(xK + bofs + offK(t0 + row, d0 + c4)) = h;
        }
    }
    __syncthreads();
#pragma unroll
    for (int it = 0; it < 2; ++it) {
        int flat = it * 256 + tid;
        int d = flat >> 3, c = (flat & 7) * 8;
        half8 hv;
#pragma unroll
        for (int j = 0; j < 8; ++j) hv[j] = (_Float16)T[(c + j) * 65 + d];
        if (isX)
            *(half8*)(xV + bofs + offV(t0 + c, d0 + d)) = hv;
        else
            *(half8*)(WT + offWT(d0 + d, t0 + c)) = hv;  // W^T[n=d0+d][k=t0+c..+7]
    }
}

// ================= flashF: fused Q-GEMM prologue + flashP main loop =========
// r11-verified (157.6us) with ONE change: the 64 loop barriers (and
// prologue-B's) are LDS-only (lgkmcnt drain, NO vmcnt drain) — K-prefetch
// and V loads genuinely span the barrier; compiler waits at first register
// use. Sx is double-buffered by phase so write-after-read across the light
// barrier cannot race.
__global__ __launch_bounds__(256, 2)
void flashF(const _Float16* __restrict__ xK, const _Float16* __restrict__ xV,
            const _Float16* __restrict__ WT, float* __restrict__ out) {
    __shared__ __align__(16) unsigned char SMEM[34816];
    float* Sx = (float*)SMEM;

    const int tid = threadIdx.x;
    const int w = tid >> 6, lane = tid & 63;
    const int r31 = lane & 31, hi = lane >> 5;
    const int laneoff = (r31 << 4) + (hi << 3);
    const int d0w = w * 128;
    const int bx = blockIdx.x;
    const int b = bx & 7;
    const int q0 = (bx >> 3) * 32;
    const size_t xb = (size_t)b * (S_ * D_);

    const _Float16* kbase = xK + xb + (w << 12) + laneoff;
    const _Float16* vbase = xV + xb + (w << 12) + laneoff;

    // ---- prologue A: Q-GEMM for this wave's k-quarter (n in [w*128,+128)) --
    half8 Qr[8];
    {
        const _Float16* aq = xK + xb + ((size_t)(q0 >> 5) << 14) + laneoff;
        const _Float16* wtb = WT + ((w * 4) << 14) + laneoff;
        f32x16 acc[4];
#pragma unroll
        for (int nt = 0; nt < 4; ++nt)
#pragma unroll
            for (int r = 0; r < 16; ++r) acc[nt][r] = 0.f;
#pragma unroll
        for (int kg = 0; kg < 4; ++kg) {
            half8 Ax[8];
#pragma unroll
            for (int k8 = 0; k8 < 8; ++k8)
                Ax[k8] = *(const half8*)(aq + ((kg * 8 + k8) << 9));
#pragma unroll
            for (int k8 = 0; k8 < 8; ++k8) {
                int kc = kg * 8 + k8;
                half8 B0 = *(const half8*)(wtb + (0 << 14) + (kc << 9));
                half8 B1 = *(const half8*)(wtb + (1 << 14) + (kc << 9));
                half8 B2 = *(const half8*)(wtb + (2 << 14) + (kc << 9));
                half8 B3 = *(const half8*)(wtb + (3 << 14) + (kc << 9));
                acc[0] = __builtin_amdgcn_mfma_f32_32x32x16_f16(Ax[k8], B0, acc[0], 0, 0, 0);
                acc[1] = __builtin_amdgcn_mfma_f32_32x32x16_f16(Ax[k8], B1, acc[1], 0, 0, 0);
                acc[2] = __builtin_amdgcn_mfma_f32_32x32x16_f16(Ax[k8], B2, acc[2], 0, 0, 0);
                acc[3] = __builtin_amdgcn_mfma_f32_32x32x16_f16(Ax[k8], B3, acc[3], 0, 0, 0);
            }
        }
        // acc -> Qr via per-nt LDS transpose (same-wave write->read, no barrier)
        float* tw = (float*)SMEM + w * 1152;
#pragma unroll
        for (int nt = 0; nt < 4; ++nt) {
#pragma unroll
            for (int r = 0; r < 16; ++r) {
                int mrow = (r & 3) + ((r >> 2) << 3) + (hi << 2);
                tw[mrow * 36 + r31] = acc[nt][r] * INV_SCALE;
            }
#pragma unroll
            for (int h2 = 0; h2 < 2; ++h2) {
                const float* tr = tw + r31 * 36 + h2 * 16 + hi * 8;
                f32x4 a = *(const f32x4*)(tr);
                f32x4 b4 = *(const f32x4*)(tr + 4);
                half8 q;
#pragma unroll
                for (int j = 0; j < 4; ++j) { q[j] = (_Float16)a[j]; q[4 + j] = (_Float16)b4[j]; }
                Qr[2 * nt + h2] = q;
            }
        }
    }
    __syncthreads();   // transpose patches done before Sx region is reused

    half8 KA[8], KB[8];
    f32x16 sS;

    // ---- prologue B: K(0)->KA, QK(0), Kpre(1)->KB, S-write(0), light BAR ----
#pragma unroll
    for (int kc = 0; kc < 8; ++kc)
        KA[kc] = *(const half8*)(kbase + (kc << 9));
    {
        f32x16 s;
#pragma unroll
        for (int r = 0; r < 16; ++r) s[r] = 0.f;
#pragma unroll
        for (int kc = 0; kc < 8; ++kc)
            s = __builtin_amdgcn_mfma_f32_32x32x16_f16(KA[kc], Qr[kc], s, 0, 0, 0);
        sS = s;
    }
#pragma unroll
    for (int kc = 0; kc < 8; ++kc)
        KB[kc] = *(const half8*)(kbase + (1 << 14) + (kc << 9));
    {
        float* sxw = Sx + w * 1024;
#pragma unroll
        for (int r2 = 0; r2 < 4; ++r2) {
            f32x4 v_ = { sS[4 * r2 + 0], sS[4 * r2 + 1], sS[4 * r2 + 2], sS[4 * r2 + 3] };
            *(f32x4*)&sxw[(r2 * 64 + lane) * 4] = v_;
        }
    }
    bar_lds();

    f32x16 O[4];
#pragma unroll
    for (int dc = 0; dc < 4; ++dc)
#pragma unroll
        for (int r = 0; r < 16; ++r) O[dc][r] = 0.f;
    float m = -1e30f, l = 0.f;

#define SMX_HEAD(TI) \
    half8 Vc[8]; \
    _Pragma("unroll") for (int dc = 0; dc < 4; ++dc) \
    _Pragma("unroll") for (int kh = 0; kh < 2; ++kh) \
        Vc[dc * 2 + kh] = *(const half8*)(vbase + ((TI) << 14) + (dc << 10) + (kh << 9)); \
    float sv[16]; \
    { \
        _Pragma("unroll") for (int i = 0; i < 16; ++i) sv[i] = sS[i]; \
        _Pragma("unroll") for (int pw = 1; pw < 4; ++pw) { \
            const float* sxp = Sx + (((TI) & 1) * 4 + (w ^ pw)) * 1024; \
            _Pragma("unroll") for (int r2 = 0; r2 < 4; ++r2) { \
                f32x4 pp = *(const f32x4*)&sxp[(r2 * 64 + lane) * 4]; \
                _Pragma("unroll") for (int j = 0; j < 4; ++j) sv[4 * r2 + j] += pp[j]; \
            } \
        } \
    } \
    float mt_ = sv[0]; \
    _Pragma("unroll") for (int i = 1; i < 16; ++i) mt_ = fmaxf(mt_, sv[i]); \
    mt_ = fmaxf(mt_, __shfl_xor(mt_, 32)); \
    if (__any(mt_ > m + 8.f)) { \
        float mn = fmaxf(m, mt_); \
        float a_ = __expf(m - mn); \
        l *= a_; \
        _Pragma("unroll") for (int dc = 0; dc < 4; ++dc) \
        _Pragma("unroll") for (int r = 0; r < 16; ++r) O[dc][r] *= a_; \
        m = mn; \
    } \
    float pa[16]; float rs = 0.f; \
    _Pragma("unroll") for (int i = 0; i < 16; ++i) { pa[i] = __expf(sv[i] - m); rs += pa[i]; } \
    l += rs + __shfl_xor(rs, 32);

#define SMX_TAILPART \
    u32 q16[8]; \
    _Pragma("unroll") for (int r2 = 0; r2 < 4; ++r2) { \
        q16[2 * r2 + 0] = pk16(pa[4 * r2 + 0], pa[4 * r2 + 1]); \
        q16[2 * r2 + 1] = pk16(pa[4 * r2 + 2], pa[4 * r2 + 3]); \
    } \
    half8 Pf[2]; \
    _Pragma("unroll") for (int kh = 0; kh < 2; ++kh) { \
        int r2o = 2 * kh + hi, r2s = 2 * kh + (hi ^ 1); \
        u32 rv0 = (u32)__shfl_xor((int)q16[2 * r2s + 0], 32); \
        u32 rv1 = (u32)__shfl_xor((int)q16[2 * r2s + 1], 32); \
        u32 o0 = q16[2 * r2o + 0], o1 = q16[2 * r2o + 1]; \
        union { u32 u[4]; half8 v; } U_; \
        U_.u[0] = hi ? rv0 : o0; U_.u[1] = hi ? rv1 : o1; \
        U_.u[2] = hi ? o0 : rv0; U_.u[3] = hi ? o1 : rv1; \
        Pf[kh] = U_.v; \
    } \
    _Pragma("unroll") for (int dc = 0; dc < 4; ++dc) { \
        O[dc] = __builtin_amdgcn_mfma_f32_32x32x16_f16(Vc[dc * 2 + 0], Pf[0], O[dc], 0, 0, 0); \
        O[dc] = __builtin_amdgcn_mfma_f32_32x32x16_f16(Vc[dc * 2 + 1], Pf[1], O[dc], 0, 0, 0); \
    }

#define PBODY(TI, KRD, KWR) do {                                                \
    SMX_HEAD(TI)                                                                \
    f32x16 sn_;                                                                 \
    {                                                                           \
        f32x16 s_;                                                              \
        _Pragma("unroll") for (int r = 0; r < 16; ++r) s_[r] = 0.f;             \
        _Pragma("unroll") for (int kc = 0; kc < 8; ++kc)                        \
            s_ = __builtin_amdgcn_mfma_f32_32x32x16_f16(KRD[kc], Qr[kc], s_, 0, 0, 0); \
        sn_ = s_;                                                               \
    }                                                                           \
    {                                                                           \
        const int tp2_ = ((TI) + 2) & 63;                                       \
        _Pragma("unroll") for (int kc = 0; kc < 8; ++kc)                        \
            KWR[kc] = *(const half8*)(kbase + (tp2_ << 14) + (kc << 9));        \
    }                                                                           \
    SMX_TAILPART                                                                \
    sS = sn_;                                                                   \
    {                                                                           \
        float* sxw = Sx + ((((TI) + 1) & 1) * 4 + w) * 1024;                    \
        _Pragma("unroll") for (int r2 = 0; r2 < 4; ++r2) {                      \
            f32x4 v_ = { sS[4 * r2 + 0], sS[4 * r2 + 1], sS[4 * r2 + 2], sS[4 * r2 + 3] }; \
            *(f32x4*)&sxw[(r2 * 64 + lane) * 4] = v_;                           \
        }                                                                       \
    }                                                                           \
    bar_lds();                                                                  \
} while (0)

    for (int tp = 0; tp < 31; ++tp) {
        PBODY(2 * tp,     KB, KA);
        PBODY(2 * tp + 1, KA, KB);
    }
    PBODY(62, KB, KA);
    {
        SMX_HEAD(63)
        SMX_TAILPART
    }
#undef PBODY
#undef SMX_HEAD
#undef SMX_TAILPART

    __syncthreads();   // full barrier before epilogue overlay of Sx region

    // ---- epilogue: O^T/l -> 2-phase LDS transpose -> coalesced stores ----
    {
        float inv = 1.0f / l;
        float* ew = (float*)SMEM + w * 2176;   // 32 q-rows x 68 (pad) per wave
        const int qq = lane >> 1, cs = (lane & 1) * 32;
#pragma unroll
        for (int ph = 0; ph < 2; ++ph) {
#pragma unroll
            for (int dc = 0; dc < 2; ++dc)
#pragma unroll
                for (int r = 0; r < 16; ++r) {
                    int dl = dc * 32 + (r & 3) + ((r >> 2) << 3) + (hi << 2);
                    ew[r31 * 68 + dl] = O[ph * 2 + dc][r] * inv;
                }
            float* gp = out + xb + (size_t)(q0 + qq) * 512 + d0w + ph * 64 + cs;
#pragma unroll
            for (int k = 0; k < 8; ++k)
                *(f32x4*)(gp + 4 * k) = *(const f32x4*)&ew[qq * 68 + cs + 4 * k];
        }
    }
}

// ================= fp32 fallback (round 1) ==================================
__global__ __launch_bounds__(256) void xw_gemm_f32(const float* __restrict__ A,
                                                   const float* __restrict__ W,
                                                   float* __restrict__ C) {
    __shared__ float As[16][65];
    __shared__ float Bs[16][64];
    const int tid = threadIdx.x;
    const int row0 = blockIdx.y * 64, col0 = blockIdx.x * 64;
    const int ty = tid / 16, tx = tid % 16;
    float acc[4][4] = {};
    const int ar = tid / 4, ak = (tid % 4) * 4, bk = tid / 16, bn = (tid % 16) * 4;
    for (int k0 = 0; k0 < 512; k0 += 16) {
        float4 a4 = *(const float4*)(A + (size_t)(row0 + ar) * 512 + k0 + ak);
        float4 b4 = *(const float4*)(W + (size_t)(k0 + bk) * 512 + col0 + bn);
        __syncthreads();
        As[ak + 0][ar] = a4.x; As[ak + 1][ar] = a4.y;
        As[ak + 2][ar] = a4.z; As[ak + 3][ar] = a4.w;
        *(float4*)&Bs[bk][bn] = b4;
        __syncthreads();
#pragma unroll
        for (int kk = 0; kk < 16; kk++) {
            float a[4], bv[4];
#pragma unroll
            for (int i = 0; i < 4; i++) a[i] = As[kk][ty * 4 + i];
#pragma unroll
            for (int j = 0; j < 4; j++) bv[j] = Bs[kk][tx * 4 + j];
#pragma unroll
            for (int i = 0; i < 4; i++)
#pragma unroll
                for (int j = 0; j < 4; j++) acc[i][j] += a[i] * bv[j];
        }
    }
#pragma unroll
    for (int i = 0; i < 4; i++) {
        float4 o = make_float4(acc[i][0] * INV_SCALE, acc[i][1] * INV_SCALE,
                               acc[i][2] * INV_SCALE, acc[i][3] * INV_SCALE);
        *(float4*)(C + (size_t)(row0 + ty * 4 + i) * 512 + col0 + tx * 4) = o;
    }
}

__global__ __launch_bounds__(256) void flash_f32(const float* __restrict__ x,
                                                 const float* __restrict__ qw,
                                                 float* __restrict__ out) {
    __shared__ float4 kt[16 * 136];
    const int tid = threadIdx.x;
    const int q = tid >> 3, g = tid & 7;
    const int blk = blockIdx.x;
    const int b = blk >> 6;
    const int qrow = (blk & 63) * 32 + q;
    const size_t xbase = (size_t)b * S_ * D_;
    float qwr[64];
    {
        const float4* p = (const float4*)(qw + xbase + (size_t)qrow * D_ + g * 64);
#pragma unroll
        for (int i4 = 0; i4 < 16; i4++) {
            float4 v = p[i4];
            qwr[4 * i4 + 0] = v.x; qwr[4 * i4 + 1] = v.y;
            qwr[4 * i4 + 2] = v.z; qwr[4 * i4 + 3] = v.w;
        }
    }
    float oa[64];
#pragma unroll
    for (int i = 0; i < 64; i++) oa[i] = 0.f;
    float m = -1e30f, l = 0.f;
    const float4* x4 = (const float4*)(x + xbase);
    for (int t0 = 0; t0 < S_; t0 += 16) {
        __syncthreads();
#pragma unroll
        for (int j = 0; j < 8; j++) {
            int f = tid + j * 256;
            int tt = f >> 7, c = f & 127;
            kt[tt * 136 + (c >> 4) * 17 + (c & 15)] = x4[(size_t)(t0 + tt) * 128 + c];
        }
        __syncthreads();
#pragma unroll 1
        for (int tt = 0; tt < 16; tt++) {
            float4 kv[16];
            const float4* kp = &kt[tt * 136 + g * 17];
#pragma unroll
            for (int i4 = 0; i4 < 16; i4++) kv[i4] = kp[i4];
            float s = 0.f;
#pragma unroll
            for (int i4 = 0; i4 < 16; i4++)
                s += qwr[4 * i4] * kv[i4].x + qwr[4 * i4 + 1] * kv[i4].y
                   + qwr[4 * i4 + 2] * kv[i4].z + qwr[4 * i4 + 3] * kv[i4].w;
            s += __shfl_xor(s, 1, 64); s += __shfl_xor(s, 2, 64); s += __shfl_xor(s, 4, 64);
            if (s > m) {
                float alpha = __expf(m - s);
                l *= alpha;
#pragma unroll
                for (int i = 0; i < 64; i++) oa[i] *= alpha;
                m = s;
            }
            float p = __expf(s - m);
            l += p;
#pragma unroll
            for (int i4 = 0; i4 < 16; i4++) {
                oa[4 * i4 + 0] += p * kv[i4].x; oa[4 * i4 + 1] += p * kv[i4].y;
                oa[4 * i4 + 2] += p * kv[i4].z; oa[4 * i4 + 3] += p * kv[i4].w;
            }
        }
    }
    float inv_l = 1.0f / l;
    float4* op = (float4*)(out + xbase + (size_t)qrow * D_ + g * 64);
#pragma unroll
    for (int i4 = 0; i4 < 16; i4++)
        op[i4] = make_float4(oa[4 * i4] * inv_l, oa[4 * i4 + 1] * inv_l,
                             oa[4 * i4 + 2] * inv_l, oa[4 * i4 + 3] * inv_l);
}

// ================= launch ====================================================
extern "C" void kernel_launch(void* const* d_in, const int* in_sizes, int n_in,
                              void* d_out, int out_size, void* d_ws, size_t ws_size,
                              hipStream_t stream) {
    const float* x = (const float*)d_in[0];
    const float* W = (const float*)d_in[1];
    float* out = (float*)d_out;

    const size_t F16 = (size_t)HSZ * sizeof(_Float16);     // 16,777,216
    const size_t off_xK = 0;
    const size_t off_xV = F16;
    const size_t off_WT = 2 * F16;
    const size_t base   = 2 * F16 + 512 * 512 * sizeof(_Float16);   // 34,078,720

    if (ws_size >= base) {
        _Float16* xK = (_Float16*)((char*)d_ws + off_xK);
        _Float16* xV = (_Float16*)((char*)d_ws + off_xV);
        _Float16* WT = (_Float16*)((char*)d_ws + off_WT);

        cvt_all<<<2112, 256, 0, stream>>>(x, W, xK, xV, WT);
        flashF<<<512, 256, 0, stream>>>(xK, xV, WT, out);
    } else {
        const size_t needf = (size_t)HSZ * sizeof(float);
        float* xw = (ws_size >= needf) ? (float*)d_ws : out;
        dim3 g1(512 / 64, (B_ * S_) / 64);
        xw_gemm_f32<<<g1, 256, 0, stream>>>(x, W, xw);
        flash_f32<<<B_ * (S_ / 32), 256, 0, stream>>>(x, xw, out);
    }
}